// Round 9
// baseline (454.309 us; speedup 1.0000x reference)
//
#include <hip/hip_runtime.h>
#include <stdint.h>

#define B_ 2
#define N_ 2048
#define C_ 512
#define H_ 8
#define D_ 64
#define TOPK_ 100
#define BN_ (B_*N_)
#define CAP_ 512

__device__ __forceinline__ int mbcnt64(unsigned long long m) {
  return __builtin_amdgcn_mbcnt_hi((unsigned)(m >> 32),
         __builtin_amdgcn_mbcnt_lo((unsigned)m, 0u));
}

// ============================================================================
// NUMERICS CONTRACT (frozen): per output element, strictly k-ascending
// single-accumulator fmaf chain; bias / *0.125 applied once at the end.
// Bit-identical to every passing round (r1/r2/r6/r7/r8). Tile shape, LDS
// layout, buffering are free; accumulation ORDER is not.
// ============================================================================

// ---- EXACT f32 proj GEMM: 128(m) x 64(c) tile, 8x4 micro, BK=32, dbuf ----
// LDS swizzle: element (k, m) stored at col m ^ ((k&28)<<1). Writes: 32 banks
// 2-way. Reads: A broadcast (4 addrs/wave), B 64 distinct words -> 2-way.
__global__ __launch_bounds__(256)
void proj128(const float* __restrict__ X0, const float* __restrict__ X1,
             const float* __restrict__ X2,
             const float* __restrict__ W0, const float* __restrict__ W1,
             const float* __restrict__ W2,
             const float* __restrict__ b0, const float* __restrict__ b1,
             const float* __restrict__ b2,
             float* __restrict__ O0, float* __restrict__ O1,
             float* __restrict__ O2, int scatter)
{
  int z = blockIdx.z;
  const float* X = (z == 0) ? X0 : ((z == 1) ? X1 : X2);
  const float* W = (z == 0) ? W0 : ((z == 1) ? W1 : W2);
  const float* bs = (z == 0) ? b0 : ((z == 1) ? b1 : b2);
  float* O = (z == 0) ? O0 : ((z == 1) ? O1 : O2);

  __shared__ float Xs[2][32][128];   // 32 KB
  __shared__ float Ws[2][32][64];    // 16 KB

  int t = threadIdx.x;
  int tr = t >> 4, tc = t & 15;
  int m0 = blockIdx.x * 128, c0 = blockIdx.y * 64;

  float acc[8][4] = {};
  float4 xr[4], wr[2];

#define PROJ_LOAD(k0) do { \
    _Pragma("unroll") for (int j = 0; j < 4; ++j) { \
      int fid = t + j * 256; int mm = fid >> 3; int dk = (fid & 7) << 2; \
      xr[j] = *(const float4*)(X + (size_t)(m0 + mm) * C_ + (k0) + dk); } \
    _Pragma("unroll") for (int j = 0; j < 2; ++j) { \
      int fid = t + j * 256; int cc = fid >> 3; int dk = (fid & 7) << 2; \
      wr[j] = *(const float4*)(W + (size_t)(c0 + cc) * C_ + (k0) + dk); } \
  } while (0)

#define PROJ_WRITE(p) do { \
    _Pragma("unroll") for (int j = 0; j < 4; ++j) { \
      int fid = t + j * 256; int mm = fid >> 3; int dk = (fid & 7) << 2; \
      int co = mm ^ (dk << 1); \
      Xs[p][dk+0][co] = xr[j].x; Xs[p][dk+1][co] = xr[j].y; \
      Xs[p][dk+2][co] = xr[j].z; Xs[p][dk+3][co] = xr[j].w; } \
    _Pragma("unroll") for (int j = 0; j < 2; ++j) { \
      int fid = t + j * 256; int cc = fid >> 3; int dk = (fid & 7) << 2; \
      int co = cc ^ (dk << 1); \
      Ws[p][dk+0][co] = wr[j].x; Ws[p][dk+1][co] = wr[j].y; \
      Ws[p][dk+2][co] = wr[j].z; Ws[p][dk+3][co] = wr[j].w; } \
  } while (0)

#define PROJ_COMPUTE(p) do { \
    _Pragma("unroll") for (int k = 0; k < 32; ++k) { \
      int sw = (k & 28) << 1; \
      float a[8], b[4]; \
      *(float4*)&a[0] = *(const float4*)&Xs[p][k][((tr << 3) ^ sw) + 0]; \
      *(float4*)&a[4] = *(const float4*)&Xs[p][k][((tr << 3) ^ sw) + 4]; \
      *(float4*)&b[0] = *(const float4*)&Ws[p][k][(tc << 2) ^ sw]; \
      _Pragma("unroll") for (int i = 0; i < 8; ++i) \
        _Pragma("unroll") for (int j = 0; j < 4; ++j) \
          acc[i][j] = fmaf(a[i], b[j], acc[i][j]); \
    } \
  } while (0)

  PROJ_LOAD(0);
  PROJ_WRITE(0);
  __syncthreads();
  int p = 0;
  for (int k0 = 0; k0 < C_; k0 += 32) {
    bool more = (k0 + 32 < C_);
    if (more) PROJ_LOAD(k0 + 32);
    PROJ_COMPUTE(p);
    if (more) {
      PROJ_WRITE(p ^ 1);
      __syncthreads();
      p ^= 1;
    }
  }

  float bv[4];
  #pragma unroll
  for (int j = 0; j < 4; ++j) bv[j] = bs[c0 + (tc << 2) + j];

  #pragma unroll
  for (int i = 0; i < 8; ++i) {
    int m = m0 + (tr << 3) + i;
    float4 o = make_float4(acc[i][0] + bv[0], acc[i][1] + bv[1],
                           acc[i][2] + bv[2], acc[i][3] + bv[3]);
    if (scatter) {
      int bb = m >> 11;
      int tok = m & (N_ - 1);
      int h = blockIdx.y;          // c0 >> 6
      *(float4*)(O + (((size_t)(bb * H_ + h) * N_) + tok) * D_ + (tc << 2)) = o;
    } else {
      *(float4*)(O + (size_t)m * C_ + c0 + (tc << 2)) = o;
    }
  }
#undef PROJ_LOAD
#undef PROJ_WRITE
#undef PROJ_COMPUTE
}

// ---- EXACT f32 QK^T: 128(n) x 64(m) tile, 8x4 micro, K=64 in 2 dbuf'd
// BK=32 halves. Per-output chain k=0..63 ascending, *0.125 at end. ----
__global__ __launch_bounds__(256)
void qk128(const float* __restrict__ qh, const float* __restrict__ kh,
           float* __restrict__ S, int slice0, int row0, int Rrows)
{
  int z = blockIdx.z;
  int slice = slice0 + z;
  const float* Q = qh + (size_t)slice * N_ * D_;
  const float* K = kh + (size_t)slice * N_ * D_;
  float* Sp = S + (size_t)z * Rrows * N_;

  __shared__ float Qs[2][32][128];   // 32 KB
  __shared__ float Ks[2][32][64];    // 16 KB

  int t = threadIdx.x;
  int tr = t >> 4, tc = t & 15;
  int n0 = blockIdx.x * 128, m0 = blockIdx.y * 64;

  float acc[8][4] = {};
  float4 xr[4], wr[2];

#define QK_LOAD(k0) do { \
    _Pragma("unroll") for (int j = 0; j < 4; ++j) { \
      int fid = t + j * 256; int nn = fid >> 3; int dk = (fid & 7) << 2; \
      xr[j] = *(const float4*)(Q + (size_t)(row0 + n0 + nn) * D_ + (k0) + dk); } \
    _Pragma("unroll") for (int j = 0; j < 2; ++j) { \
      int fid = t + j * 256; int mm = fid >> 3; int dk = (fid & 7) << 2; \
      wr[j] = *(const float4*)(K + (size_t)(m0 + mm) * D_ + (k0) + dk); } \
  } while (0)

#define QK_WRITE(p) do { \
    _Pragma("unroll") for (int j = 0; j < 4; ++j) { \
      int fid = t + j * 256; int nn = fid >> 3; int dk = (fid & 7) << 2; \
      int co = nn ^ (dk << 1); \
      Qs[p][dk+0][co] = xr[j].x; Qs[p][dk+1][co] = xr[j].y; \
      Qs[p][dk+2][co] = xr[j].z; Qs[p][dk+3][co] = xr[j].w; } \
    _Pragma("unroll") for (int j = 0; j < 2; ++j) { \
      int fid = t + j * 256; int mm = fid >> 3; int dk = (fid & 7) << 2; \
      int co = mm ^ (dk << 1); \
      Ks[p][dk+0][co] = wr[j].x; Ks[p][dk+1][co] = wr[j].y; \
      Ks[p][dk+2][co] = wr[j].z; Ks[p][dk+3][co] = wr[j].w; } \
  } while (0)

#define QK_COMPUTE(p) do { \
    _Pragma("unroll") for (int k = 0; k < 32; ++k) { \
      int sw = (k & 28) << 1; \
      float a[8], b[4]; \
      *(float4*)&a[0] = *(const float4*)&Qs[p][k][((tr << 3) ^ sw) + 0]; \
      *(float4*)&a[4] = *(const float4*)&Qs[p][k][((tr << 3) ^ sw) + 4]; \
      *(float4*)&b[0] = *(const float4*)&Ks[p][k][(tc << 2) ^ sw]; \
      _Pragma("unroll") for (int i = 0; i < 8; ++i) \
        _Pragma("unroll") for (int j = 0; j < 4; ++j) \
          acc[i][j] = fmaf(a[i], b[j], acc[i][j]); \
    } \
  } while (0)

  QK_LOAD(0);
  QK_WRITE(0);
  __syncthreads();
  QK_LOAD(32);
  QK_COMPUTE(0);
  QK_WRITE(1);
  __syncthreads();
  QK_COMPUTE(1);

  const float scale = 0.125f;
  #pragma unroll
  for (int i = 0; i < 8; ++i) {
    int n = n0 + (tr << 3) + i;
    float4 o = make_float4(acc[i][0] * scale, acc[i][1] * scale,
                           acc[i][2] * scale, acc[i][3] * scale);
    *(float4*)(Sp + (size_t)n * N_ + m0 + (tc << 2)) = o;
  }
#undef QK_LOAD
#undef QK_WRITE
#undef QK_COMPUTE
}

// ---- one wave per row: exact radix-select of 100th largest -> softmax over
// kept -> compaction -> gather-PV (byte-identical to r8) ----
__global__ __launch_bounds__(256)
void topk_softmax_pv(const float* __restrict__ S, const float* __restrict__ vh,
                     float* __restrict__ outp, int slice0, int row0, int log2R)
{
  __shared__ float wL[4][CAP_];
  __shared__ unsigned short iL[4][CAP_];

  int t = threadIdx.x;
  int wv = t >> 6;
  int lane = t & 63;
  int gr = blockIdx.x * 4 + wv;
  int s_local = gr >> log2R;
  int rrow = gr & ((1 << log2R) - 1);
  int slice = slice0 + s_local;
  int row = row0 + rrow;

  const float* Srow = S + ((size_t)gr) * N_;

  float x[32];
  #pragma unroll
  for (int i = 0; i < 8; ++i) {
    float4 v = *(const float4*)(Srow + i * 256 + lane * 4);
    x[i*4+0] = v.x; x[i*4+1] = v.y; x[i*4+2] = v.z; x[i*4+3] = v.w;
  }
  unsigned u[32];
  #pragma unroll
  for (int i = 0; i < 32; ++i) {
    unsigned bits = __float_as_uint(x[i]);
    u[i] = bits ^ ((unsigned)(((int)bits) >> 31) | 0x80000000u);
  }

  unsigned thr = 0u;
  for (int bit = 31; bit >= 0; --bit) {
    unsigned cand = thr | (1u << bit);
    int cnt = 0;
    #pragma unroll
    for (int i = 0; i < 32; ++i) {
      unsigned long long m = __ballot(u[i] >= cand);
      cnt += __popcll(m);
    }
    if (cnt >= TOPK_) {
      thr = cand;
      if (cnt == TOPK_) break;   // exact: kept set {u>=cand} is final
    }
  }

  float mx = -1e30f;
  #pragma unroll
  for (int i = 0; i < 32; ++i) mx = fmaxf(mx, x[i]);
  #pragma unroll
  for (int off = 32; off >= 1; off >>= 1) mx = fmaxf(mx, __shfl_xor(mx, off));

  float s = 0.f;
  #pragma unroll
  for (int i = 0; i < 32; ++i) {
    bool kp = (u[i] >= thr);
    float ev = kp ? __expf(x[i] - mx) : 0.f;
    x[i] = ev;
    s += ev;
  }
  #pragma unroll
  for (int off = 32; off >= 1; off >>= 1) s += __shfl_xor(s, off);
  float inv = 1.f / s;

  int base = 0;
  #pragma unroll
  for (int i = 0; i < 32; ++i) {
    bool kp = (u[i] >= thr);
    unsigned long long m = __ballot(kp);
    if (kp) {
      int pos = base + mbcnt64(m);
      if (pos < CAP_) {
        wL[wv][pos] = x[i] * inv;
        iL[wv][pos] = (unsigned short)((i >> 2) * 256 + lane * 4 + (i & 3));
      }
    }
    base += __popcll(m);
  }
  int total = base < CAP_ ? base : CAP_;

  const float* Vs = vh + (size_t)slice * N_ * D_;
  float a0=0.f,a1=0.f,a2=0.f,a3=0.f,a4=0.f,a5=0.f,a6=0.f,a7=0.f;
  int e = 0;
  for (; e + 8 <= total; e += 8) {
    float w0=wL[wv][e+0], w1=wL[wv][e+1], w2=wL[wv][e+2], w3=wL[wv][e+3];
    float w4=wL[wv][e+4], w5=wL[wv][e+5], w6=wL[wv][e+6], w7=wL[wv][e+7];
    int j0=iL[wv][e+0], j1=iL[wv][e+1], j2=iL[wv][e+2], j3=iL[wv][e+3];
    int j4=iL[wv][e+4], j5=iL[wv][e+5], j6=iL[wv][e+6], j7=iL[wv][e+7];
    float v0=Vs[(size_t)j0*D_+lane], v1=Vs[(size_t)j1*D_+lane];
    float v2=Vs[(size_t)j2*D_+lane], v3=Vs[(size_t)j3*D_+lane];
    float v4=Vs[(size_t)j4*D_+lane], v5=Vs[(size_t)j5*D_+lane];
    float v6=Vs[(size_t)j6*D_+lane], v7=Vs[(size_t)j7*D_+lane];
    a0 = fmaf(w0, v0, a0); a1 = fmaf(w1, v1, a1);
    a2 = fmaf(w2, v2, a2); a3 = fmaf(w3, v3, a3);
    a4 = fmaf(w4, v4, a4); a5 = fmaf(w5, v5, a5);
    a6 = fmaf(w6, v6, a6); a7 = fmaf(w7, v7, a7);
  }
  for (; e < total; ++e)
    a0 = fmaf(wL[wv][e], Vs[(size_t)iL[wv][e] * D_ + lane], a0);
  float acc = ((a0 + a1) + (a2 + a3)) + ((a4 + a5) + (a6 + a7));

  int b = slice >> 3;
  int h = slice & 7;
  outp[((size_t)(b * N_ + row)) * C_ + h * D_ + lane] = acc;
}

extern "C" void kernel_launch(void* const* d_in, const int* in_sizes, int n_in,
                              void* d_out, int out_size, void* d_ws, size_t ws_size,
                              hipStream_t stream) {
  const float* q  = (const float*)d_in[0];
  const float* k  = (const float*)d_in[1];
  const float* v  = (const float*)d_in[2];
  const float* Wq = (const float*)d_in[3];
  const float* bq = (const float*)d_in[4];
  const float* Wk = (const float*)d_in[5];
  const float* bk = (const float*)d_in[6];
  const float* Wv = (const float*)d_in[7];
  const float* bv = (const float*)d_in[8];
  const float* Wp = (const float*)d_in[9];
  const float* bp = (const float*)d_in[10];

  const size_t NB = (size_t)B_ * H_ * N_ * D_;   // 2,097,152 floats
  float* qh  = (float*)d_ws;
  float* kh  = qh + NB;
  float* vh  = kh + NB;
  float* pre = vh + NB;
  float* S   = pre + NB;

  size_t fixedB = 4 * NB * sizeof(float);              // 32 MB
  size_t sliceB = (size_t)N_ * N_ * sizeof(float);     // 16.78 MB
  size_t avail = (ws_size > fixedB) ? ws_size - fixedB : 0;

  int ns = 1, R = 2048;
  if      (avail >= 4 * sliceB) { ns = 4; R = 2048; }
  else if (avail >= 2 * sliceB) { ns = 2; R = 2048; }
  else if (avail >= 1 * sliceB) { ns = 1; R = 2048; }
  else if (avail >= sliceB / 2) { ns = 1; R = 1024; }
  else                          { ns = 1; R = 512;  }
  int log2R = (R == 2048) ? 11 : ((R == 1024) ? 10 : 9);

  dim3 blk(256);

  // Q/K/V projections: exact f32 chain, head-scatter
  proj128<<<dim3(BN_/128, C_/64, 3), blk, 0, stream>>>(
      q, k, v, Wq, Wk, Wv, bq, bk, bv, qh, kh, vh, 1);

  for (int s0 = 0; s0 < B_ * H_; s0 += ns) {
    int cur = (B_ * H_ - s0) < ns ? (B_ * H_ - s0) : ns;
    for (int r0 = 0; r0 < N_; r0 += R) {
      qk128<<<dim3(R/128, N_/64, cur), blk, 0, stream>>>(qh, kh, S, s0, r0, R);
      topk_softmax_pv<<<dim3(cur * (R/4)), blk, 0, stream>>>(S, vh, pre, s0, r0, log2R);
    }
  }

  // final projection -> d_out
  proj128<<<dim3(BN_/128, C_/64, 1), blk, 0, stream>>>(
      pre, pre, pre, Wp, Wp, Wp, bp, bp, bp,
      (float*)d_out, (float*)d_out, (float*)d_out, 0);
}